// Round 5
// baseline (234.318 us; speedup 1.0000x reference)
//
#include <hip/hip_runtime.h>

typedef __attribute__((ext_vector_type(8))) short short8;
typedef __attribute__((ext_vector_type(4))) float f32x4;

#define MFMA_BF16 __builtin_amdgcn_mfma_f32_16x16x32_bf16

__device__ __forceinline__ unsigned short f2bf(float f) {
  unsigned u = __builtin_bit_cast(unsigned, f);
  u += 0x7fffu + ((u >> 16) & 1u);
  return (unsigned short)(u >> 16);
}

// ---------------- fused fp32 -> bf16 convert for all 5 inputs ----------------
__global__ __launch_bounds__(256) void f2b5_kernel(const float* __restrict__ x,
                                                   const float* __restrict__ wq,
                                                   const float* __restrict__ wk,
                                                   const float* __restrict__ wv,
                                                   const float* __restrict__ wo,
                                                   unsigned short* __restrict__ xb,
                                                   unsigned short* __restrict__ wb,
                                                   unsigned short* __restrict__ wob) {
  const int b = blockIdx.x;
  const float* src;
  unsigned short* dst;
  int base;
  if (b < 4096)      { src = x;  dst = xb;                base = b; }
  else if (b < 8192) { src = wq; dst = wb;                base = b - 4096; }
  else if (b < 9216) { src = wk; dst = wb + 2048 * 2048;  base = b - 8192; }
  else if (b < 10240){ src = wv; dst = wb + 2560 * 2048;  base = b - 9216; }
  else               { src = wo; dst = wob;               base = b - 10240; }
  const int i = base * 256 + threadIdx.x;
  const float4 v = ((const float4*)src)[i];
  ushort4 o = make_ushort4(f2bf(v.x), f2bf(v.y), f2bf(v.z), f2bf(v.w));
  ((ushort4*)dst)[i] = o;
}

// ---------------- RoPE trig table: [N][32] cos/sin (f64 once, tiny) ----------------
__global__ __launch_bounds__(256) void trig_kernel(float* __restrict__ cosT, float* __restrict__ sinT) {
  int i = blockIdx.x * 256 + threadIdx.x;  // [0, 2048*32)
  int n = i >> 5, f = i & 31;
  double ang = (double)n * pow(10000.0, -(double)f / 32.0);
  cosT[i] = (float)cos(ang);
  sinT[i] = (float)sin(ang);
}

// ---------------- bf16 NT GEMM, 2-phase double-buffered, split-K ----------------
// C[M][N] (+)= A[M][K-chunk] * B[N][K-chunk]^T ; chunk = blockIdx.z*KC .. +KC
// ATOMIC: accumulate partial into C via atomicAdd (C must be zeroed first).
template <bool ATOMIC>
__global__ __launch_bounds__(256) void gemm_bt(const short* __restrict__ A,
                                               const short* __restrict__ B,
                                               float* __restrict__ C,
                                               int M, int N, int K, int KC) {
  __shared__ __align__(16) short As[2][128 * 32];
  __shared__ __align__(16) short Bs[2][128 * 32];
  const int tid = threadIdx.x;
  const int w = tid >> 6, lane = tid & 63;
  const int fr = lane & 15, fs = lane >> 4;
  const size_t brow = (size_t)blockIdx.y * 128, bcol = (size_t)blockIdx.x * 128;
  const int wr = (w >> 1) * 64, wc = (w & 1) * 64;
  const int lr = tid >> 2;          // staging row 0..63 (+64 for 2nd issue)
  const int lc = (tid & 3) * 8;     // staging col (8 bf16 = 16B per lane)
  const int ks = blockIdx.z * KC;
  const short* ga = A + (brow + lr) * (size_t)K + lc + ks;
  const short* gb = B + (bcol + lr) * (size_t)K + lc + ks;
  f32x4 acc[4][4] = {};

  auto stage = [&](int sb, int k0) {
    short* lA = As[sb] + w * 512;   // wave-uniform LDS dest (HW: base + lane*16B)
    short* lB = Bs[sb] + w * 512;
    __builtin_amdgcn_global_load_lds((__attribute__((address_space(1))) void*)(ga + k0),
                                     (__attribute__((address_space(3))) void*)(lA), 16, 0, 0);
    __builtin_amdgcn_global_load_lds((__attribute__((address_space(1))) void*)(ga + (size_t)64 * K + k0),
                                     (__attribute__((address_space(3))) void*)(lA + 2048), 16, 0, 0);
    __builtin_amdgcn_global_load_lds((__attribute__((address_space(1))) void*)(gb + k0),
                                     (__attribute__((address_space(3))) void*)(lB), 16, 0, 0);
    __builtin_amdgcn_global_load_lds((__attribute__((address_space(1))) void*)(gb + (size_t)64 * K + k0),
                                     (__attribute__((address_space(3))) void*)(lB + 2048), 16, 0, 0);
  };

  const int nk = KC >> 5;
  stage(0, 0);
  __syncthreads();                  // drain prologue loads
  int buf = 0;
  for (int t = 0; t < nk; ++t) {
    if (t + 1 < nk) stage(buf ^ 1, (t + 1) * 32);  // issue next-tile loads (in flight over MFMA)
    short8 af[4], bfr[4];
#pragma unroll
    for (int m = 0; m < 4; ++m)
      af[m] = *(const short8*)(As[buf] + (wr + m * 16 + fr) * 32 + fs * 8);
#pragma unroll
    for (int n = 0; n < 4; ++n)
      bfr[n] = *(const short8*)(Bs[buf] + (wc + n * 16 + fr) * 32 + fs * 8);
#pragma unroll
    for (int m = 0; m < 4; ++m)
#pragma unroll
      for (int n = 0; n < 4; ++n)
        acc[m][n] = MFMA_BF16(af[m], bfr[n], acc[m][n], 0, 0, 0);
    __syncthreads();                // vmcnt(0)+barrier: next tile staged, this buf free
    buf ^= 1;
  }
#pragma unroll
  for (int m = 0; m < 4; ++m)
#pragma unroll
    for (int n = 0; n < 4; ++n)
#pragma unroll
      for (int j = 0; j < 4; ++j) {
        float* cp = &C[(brow + wr + m * 16 + fs * 4 + j) * (size_t)N + bcol + wc + n * 16 + fr];
        if (ATOMIC) atomicAdd(cp, acc[m][n][j]);
        else *cp = acc[m][n][j];
      }
}

// ---------------- fused QK-RMSNorm + RoPE + scatter to head-major layouts ----------------
// qkv: [N][3072] fp32 (q 0:2048 | k 2048:2560 | v 2560:3072)
// qb: [H][N][64] bf16 (Q pre-scaled by D^-0.5 * log2e) ; kb: [KV][N][64] ; vbt: [KV][64][N]
__global__ __launch_bounds__(256) void prep_kernel(const float* __restrict__ qkv,
                                                   const float* __restrict__ qw,
                                                   const float* __restrict__ kw,
                                                   const float* __restrict__ cosT,
                                                   const float* __restrict__ sinT,
                                                   short* __restrict__ qb,
                                                   short* __restrict__ kb,
                                                   short* __restrict__ vbt) {
  const int n = blockIdx.x, t = threadIdx.x;
  const int w = t >> 6, lane = t & 63;
  __shared__ float redq[4], redk[4];
  const float* row = qkv + (size_t)n * 3072;
  const float* cT = cosT + n * 32;
  const float* sT = sinT + n * 32;
  // --- Q: 2048 elems, 8/thread, norm over full 2048 ---
  const float4* r4 = (const float4*)row;
  float4 a = r4[t * 2], b = r4[t * 2 + 1];
  float ss = a.x*a.x + a.y*a.y + a.z*a.z + a.w*a.w + b.x*b.x + b.y*b.y + b.z*b.z + b.w*b.w;
#pragma unroll
  for (int off = 32; off > 0; off >>= 1) ss += __shfl_xor(ss, off);
  if (lane == 0) redq[w] = ss;
  __syncthreads();
  // fold D^-0.5 and log2(e) (scores in log2-domain for exp2-based softmax)
  float rsq = rsqrtf((redq[0] + redq[1] + redq[2] + redq[3]) * (1.0f / 2048.f) + 1e-6f)
              * 0.125f * 1.44269504088896f;
  const int base = t * 8;
  float y[8] = {a.x, a.y, a.z, a.w, b.x, b.y, b.z, b.w};
#pragma unroll
  for (int e = 0; e < 8; ++e) y[e] *= rsq * qw[base + e];
  short8 ov;
  const int dbase = base & 63;
#pragma unroll
  for (int p = 0; p < 4; ++p) {
    float c = cT[(dbase >> 1) + p], s = sT[(dbase >> 1) + p];
    float x1 = y[2 * p], x2 = y[2 * p + 1];
    ov[2 * p]     = (short)f2bf(x1 * c - x2 * s);
    ov[2 * p + 1] = (short)f2bf(x1 * s + x2 * c);
  }
  const int h = base >> 6;
  *(short8*)(qb + ((size_t)h * 2048 + n) * 64 + dbase) = ov;
  // --- K: 512 elems, 2/thread, norm over full 512 ---
  const int ki = t * 2;
  float2 kv2 = *(const float2*)(row + 2048 + ki);
  float ssk = kv2.x * kv2.x + kv2.y * kv2.y;
#pragma unroll
  for (int off = 32; off > 0; off >>= 1) ssk += __shfl_xor(ssk, off);
  if (lane == 0) redk[w] = ssk;
  __syncthreads();
  float rsk = rsqrtf((redk[0] + redk[1] + redk[2] + redk[3]) * (1.0f / 512.f) + 1e-6f);
  float z0 = kv2.x * rsk * kw[ki], z1 = kv2.y * rsk * kw[ki + 1];
  const int kd = ki & 63, kvh = ki >> 6;
  {
    float c = cT[kd >> 1], s = sT[kd >> 1];
    ushort2 o2 = make_ushort2(f2bf(z0 * c - z1 * s), f2bf(z0 * s + z1 * c));
    *(ushort2*)(kb + ((size_t)kvh * 2048 + n) * 64 + kd) = o2;
  }
  // --- V: bf16 + transpose store [KV][64][N] ---
  float2 vv = *(const float2*)(row + 2560 + ki);
  vbt[((size_t)kvh * 64 + kd) * 2048 + n]       = (short)f2bf(vv.x);
  vbt[((size_t)kvh * 64 + kd + 1) * 2048 + n]   = (short)f2bf(vv.y);
}

// ---------------- causal GQA flash attention v4 ----------------
// 1D grid of 1024 blocks, longest-first (qblk = 31 - bid>>5) for LPT balance.
// Block = (head, 64 q-rows); 4 waves * 16 rows. KVBLK=64. LDS = 40 KB -> 4 blocks/CU.
// Every wave computes every tile (QBLK == KVBLK): no skip divergence, 1 masked tile/wave.
__global__ __launch_bounds__(256, 4) void attn_kernel(const short* __restrict__ qb,
                                                      const short* __restrict__ kb,
                                                      const short* __restrict__ vbt,
                                                      short* __restrict__ ab) {
  const int bid = blockIdx.x;
  const int h = bid & 31;
  const int qblk = 31 - (bid >> 5);       // longest blocks dispatch first
  const int kvh = h >> 2;                 // G=4
  const int tid = threadIdx.x;
  const int w = tid >> 6, lane = tid & 63;
  const int fr = lane & 15, fs = lane >> 4;
  const int q0w = qblk * 64 + w * 16;     // this wave's first q row
  __shared__ __align__(16) short Ks[2][64][64];  // [buf][kv][d], chunk c holds global chunk c^(kv&7)
  __shared__ __align__(16) short Vs[2][64][64];  // [buf][d][kv], chunk c holds global chunk c^(d&7)
  __shared__ __align__(16) short Ps[4][16][64];  // per-wave P, chunk-XOR-swizzled (no pad)
  const short* Kb = kb + (size_t)kvh * 2048 * 64;
  const short* Vb = vbt + (size_t)kvh * 64 * 2048;
  short8 qf[2];
  {
    const short* qrow = qb + ((size_t)h * 2048 + q0w + fr) * 64;
    qf[0] = *(const short8*)(qrow + fs * 8);
    qf[1] = *(const short8*)(qrow + 32 + fs * 8);
  }
  short8 ones8;
#pragma unroll
  for (int e = 0; e < 8; ++e) ones8[e] = (short)0x3F80;  // bf16 1.0
  f32x4 accO[4] = {};
  f32x4 lacc = {};                         // row-sum accumulator (via ones-MFMA)
  float mrow[4] = {-1e30f, -1e30f, -1e30f, -1e30f};

  const int rS = lane >> 3;               // staging row within 8-row strip
  const int cS = (lane & 7) ^ rS;         // pre-swizzled source chunk
  auto stage = [&](int sb, int kv0s) {
#pragma unroll
    for (int i = 0; i < 2; ++i) {
      int r = i * 32 + w * 8 + rS;        // r & 7 == rS
      __builtin_amdgcn_global_load_lds(
          (__attribute__((address_space(1))) void*)(Kb + (size_t)(kv0s + r) * 64 + cS * 8),
          (__attribute__((address_space(3))) void*)(&Ks[sb][0][0] + i * 2048 + w * 512), 16, 0, 0);
      __builtin_amdgcn_global_load_lds(
          (__attribute__((address_space(1))) void*)(Vb + (size_t)r * 2048 + kv0s + cS * 8),
          (__attribute__((address_space(3))) void*)(&Vs[sb][0][0] + i * 2048 + w * 512), 16, 0, 0);
    }
  };

  const int ntiles = qblk + 1;
  int buf = 0;
  stage(0, 0);
  __syncthreads();
  for (int t = 0; t < ntiles; ++t) {
    const int kv0 = t * 64;
    if (t + 1 < ntiles) stage(buf ^ 1, (t + 1) * 64);
    const short* KsB = &Ks[buf][0][0];
    const short* VsB = &Vs[buf][0][0];
    const int sw = (fr & 7);
    // ---- QK^T (scores in log2-domain; Q pre-scaled by D^-0.5*log2e) ----
    f32x4 sc[4];
#pragma unroll
    for (int ct = 0; ct < 4; ++ct) {
      const int rk = ct * 16 + fr;
      short8 kf0 = *(const short8*)(KsB + rk * 64 + ((fs ^ sw) * 8));
      short8 kf1 = *(const short8*)(KsB + rk * 64 + (((4 + fs) ^ sw) * 8));
      f32x4 a = {};
      a = MFMA_BF16(qf[0], kf0, a, 0, 0, 0);
      a = MFMA_BF16(qf[1], kf1, a, 0, 0, 0);
      sc[ct] = a;
    }
    // ---- causal mask (exactly the last tile per wave) ----
    if (t == qblk) {
#pragma unroll
      for (int ct = 0; ct < 4; ++ct) {
        const int col = kv0 + ct * 16 + fr;
#pragma unroll
        for (int j = 0; j < 4; ++j)
          if (col > q0w + fs * 4 + j) sc[ct][j] = -1e30f;
      }
    }
    // ---- online softmax: row max + defer-max (T13, THR=8 in log2-domain) ----
    float pmax[4];
    int defer_ok = 1;
#pragma unroll
    for (int j = 0; j < 4; ++j) {
      float v = fmaxf(fmaxf(sc[0][j], sc[1][j]), fmaxf(sc[2][j], sc[3][j]));
#pragma unroll
      for (int off = 1; off < 16; off <<= 1) v = fmaxf(v, __shfl_xor(v, off));
      pmax[j] = v;
      defer_ok &= (v - mrow[j] <= 8.0f);
    }
    if (!__all(defer_ok)) {  // rescale path (rare after warm-up)
      float resc[4];
#pragma unroll
      for (int j = 0; j < 4; ++j) {
        float mn = fmaxf(mrow[j], pmax[j]);
        resc[j] = exp2f(mrow[j] - mn);
        mrow[j] = mn;
        lacc[j] *= resc[j];
      }
#pragma unroll
      for (int dt = 0; dt < 4; ++dt)
#pragma unroll
        for (int j = 0; j < 4; ++j) accO[dt][j] *= resc[j];
    }
    // ---- P = exp2(sc - m), store bf16 to LDS (chunk-XOR-swizzled cols) ----
#pragma unroll
    for (int ct = 0; ct < 4; ++ct)
#pragma unroll
      for (int j = 0; j < 4; ++j) {
        const int r = fs * 4 + j;
        Ps[w][r][(ct * 16 + fr) ^ ((r & 7) << 3)] = (short)f2bf(exp2f(sc[ct][j] - mrow[j]));
      }
    // ---- P·V + row-sum via ones-MFMA ----
    short8 pa[2];
#pragma unroll
    for (int s = 0; s < 2; ++s)
      pa[s] = *(const short8*)(&Ps[w][fr][((s * 4 + fs) ^ (fr & 7)) * 8]);
    lacc = MFMA_BF16(pa[0], ones8, lacc, 0, 0, 0);
    lacc = MFMA_BF16(pa[1], ones8, lacc, 0, 0, 0);
#pragma unroll
    for (int dt = 0; dt < 4; ++dt) {
      const int rv = dt * 16 + fr;
      short8 vf0 = *(const short8*)(VsB + rv * 64 + ((fs ^ sw) * 8));
      short8 vf1 = *(const short8*)(VsB + rv * 64 + (((4 + fs) ^ sw) * 8));
      accO[dt] = MFMA_BF16(pa[0], vf0, accO[dt], 0, 0, 0);
      accO[dt] = MFMA_BF16(pa[1], vf1, accO[dt], 0, 0, 0);
    }
    __syncthreads();
    buf ^= 1;
  }
  // ---- epilogue: normalize + store [N][H*D] bf16 ----
  float invl[4];
#pragma unroll
  for (int j = 0; j < 4; ++j) invl[j] = 1.0f / lacc[j];
#pragma unroll
  for (int dt = 0; dt < 4; ++dt)
#pragma unroll
    for (int j = 0; j < 4; ++j)
      ab[(size_t)(q0w + fs * 4 + j) * 2048 + h * 64 + dt * 16 + fr] =
          (short)f2bf(accO[dt][j] * invl[j]);
}

extern "C" void kernel_launch(void* const* d_in, const int* in_sizes, int n_in,
                              void* d_out, int out_size, void* d_ws, size_t ws_size,
                              hipStream_t stream) {
  const float* x  = (const float*)d_in[0];
  const float* wq = (const float*)d_in[1];
  const float* wk = (const float*)d_in[2];
  const float* wv = (const float*)d_in[3];
  const float* wo = (const float*)d_in[4];
  const float* qw = (const float*)d_in[5];
  const float* kw = (const float*)d_in[6];
  float* out = (float*)d_out;
  char* ws = (char*)d_ws;
  short* xb   = (short*)(ws + 0);          // 8 MB  : x bf16, then attn-out bf16
  short* wb   = (short*)(ws + 8388608);    // 12 MB : [wq;wk;wv] bf16 [3072][2048]
  short* wob  = (short*)(ws + 20971520);   // 8 MB  : wo bf16
  float* qkvf = (float*)(ws + 29360128);   // 24 MB : qkv fp32 [2048][3072]
  short* qb   = (short*)(ws + 54525952);   // 8 MB  : q roped+scaled [32][2048][64]
  short* kb   = (short*)(ws + 62914560);   // 2 MB  : k roped [8][2048][64]
  short* vbt  = (short*)(ws + 65011712);   // 2 MB  : v^T [8][64][2048]
  float* cosT = (float*)(ws + 67108864);   // 256 KB
  float* sinT = (float*)(ws + 67371008);   // 256 KB
  short* ab = xb;

  hipMemsetAsync(qkvf, 0, 2048 * 3072 * sizeof(float), stream);
  hipMemsetAsync(out, 0, 2048 * 2048 * sizeof(float), stream);
  f2b5_kernel<<<14336, 256, 0, stream>>>(x, wq, wk, wv, wo,
                                         (unsigned short*)xb, (unsigned short*)wb,
                                         (unsigned short*)wob);
  trig_kernel<<<256, 256, 0, stream>>>(cosT, sinT);
  gemm_bt<true><<<dim3(24, 16, 2), 256, 0, stream>>>(xb, wb, qkvf, 2048, 3072, 2048, 1024);
  prep_kernel<<<2048, 256, 0, stream>>>(qkvf, qw, kw, cosT, sinT, qb, kb, vbt);
  attn_kernel<<<1024, 256, 0, stream>>>(qb, kb, vbt, ab);
  gemm_bt<true><<<dim3(16, 16, 4), 256, 0, stream>>>(ab, wob, out, 2048, 2048, 2048, 512);
}

// Round 6
// 166.841 us; speedup vs baseline: 1.4044x; 1.4044x over previous
//
#include <hip/hip_runtime.h>

typedef __attribute__((ext_vector_type(8))) short short8;
typedef __attribute__((ext_vector_type(4))) float f32x4;

#define MFMA_BF16 __builtin_amdgcn_mfma_f32_16x16x32_bf16

__device__ __forceinline__ unsigned short f2bf(float f) {
  unsigned u = __builtin_bit_cast(unsigned, f);
  u += 0x7fffu + ((u >> 16) & 1u);
  return (unsigned short)(u >> 16);
}

// ---------------- fused fp32 -> bf16 convert for all 5 inputs ----------------
__global__ __launch_bounds__(256) void f2b5_kernel(const float* __restrict__ x,
                                                   const float* __restrict__ wq,
                                                   const float* __restrict__ wk,
                                                   const float* __restrict__ wv,
                                                   const float* __restrict__ wo,
                                                   unsigned short* __restrict__ xb,
                                                   unsigned short* __restrict__ wb,
                                                   unsigned short* __restrict__ wob) {
  const int b = blockIdx.x;
  const float* src;
  unsigned short* dst;
  int base;
  if (b < 4096)      { src = x;  dst = xb;                base = b; }
  else if (b < 8192) { src = wq; dst = wb;                base = b - 4096; }
  else if (b < 9216) { src = wk; dst = wb + 2048 * 2048;  base = b - 8192; }
  else if (b < 10240){ src = wv; dst = wb + 2560 * 2048;  base = b - 9216; }
  else               { src = wo; dst = wob;               base = b - 10240; }
  const int i = base * 256 + threadIdx.x;
  const float4 v = ((const float4*)src)[i];
  ushort4 o = make_ushort4(f2bf(v.x), f2bf(v.y), f2bf(v.z), f2bf(v.w));
  ((ushort4*)dst)[i] = o;
}

// ---------------- RoPE trig table: [N][32] cos/sin (f64 once, tiny) ----------------
__global__ __launch_bounds__(256) void trig_kernel(float* __restrict__ cosT, float* __restrict__ sinT) {
  int i = blockIdx.x * 256 + threadIdx.x;  // [0, 2048*32)
  int n = i >> 5, f = i & 31;
  double ang = (double)n * pow(10000.0, -(double)f / 32.0);
  cosT[i] = (float)cos(ang);
  sinT[i] = (float)sin(ang);
}

// ---------------- split-K partial reduce: out = a + b (float4 x2 per thread) ----------------
__global__ __launch_bounds__(256) void add2_kernel(const float* __restrict__ a,
                                                   const float* __restrict__ b,
                                                   float* __restrict__ o) {
  int i = blockIdx.x * 256 + threadIdx.x;
#pragma unroll
  for (int s = 0; s < 2; ++s) {
    const float4 u = ((const float4*)a)[i], v = ((const float4*)b)[i];
    ((float4*)o)[i] = make_float4(u.x + v.x, u.y + v.y, u.z + v.z, u.w + v.w);
    i += 524288;
  }
}

// ---------------- bf16 NT GEMM, 2-phase double-buffered, split-K to partials ----------------
// C_z[M][N] = A[M][Kchunk_z] * B[N][Kchunk_z]^T ; z-slice writes C + z*M*N (plain stores).
// LDS chunk-XOR swizzle: LDS chunk c of row r holds global chunk c^(r&3)  (pre-swizzled src).
__global__ __launch_bounds__(256) void gemm_bt(const short* __restrict__ A,
                                               const short* __restrict__ B,
                                               float* __restrict__ C,
                                               int M, int N, int K, int KC) {
  __shared__ __align__(16) short As[2][128 * 32];
  __shared__ __align__(16) short Bs[2][128 * 32];
  const int tid = threadIdx.x;
  const int w = tid >> 6, lane = tid & 63;
  const int fr = lane & 15, fs = lane >> 4;
  const size_t brow = (size_t)blockIdx.y * 128, bcol = (size_t)blockIdx.x * 128;
  const int wr = (w >> 1) * 64, wc = (w & 1) * 64;
  const int lr = tid >> 2;          // staging row 0..63 (+64 for 2nd issue)
  const int lcS = ((tid & 3) ^ (lr & 3)) * 8;  // pre-swizzled source chunk (8 bf16 = 16B)
  const int ks = blockIdx.z * KC;
  C += (size_t)blockIdx.z * ((size_t)M * N);   // partial buffer for this z-slice
  const short* ga = A + (brow + lr) * (size_t)K + lcS + ks;
  const short* gb = B + (bcol + lr) * (size_t)K + lcS + ks;
  f32x4 acc[4][4] = {};

  auto stage = [&](int sb, int k0) {
    short* lA = As[sb] + w * 512;   // wave-uniform LDS dest (HW: base + lane*16B)
    short* lB = Bs[sb] + w * 512;
    __builtin_amdgcn_global_load_lds((__attribute__((address_space(1))) void*)(ga + k0),
                                     (__attribute__((address_space(3))) void*)(lA), 16, 0, 0);
    __builtin_amdgcn_global_load_lds((__attribute__((address_space(1))) void*)(ga + (size_t)64 * K + k0),
                                     (__attribute__((address_space(3))) void*)(lA + 2048), 16, 0, 0);
    __builtin_amdgcn_global_load_lds((__attribute__((address_space(1))) void*)(gb + k0),
                                     (__attribute__((address_space(3))) void*)(lB), 16, 0, 0);
    __builtin_amdgcn_global_load_lds((__attribute__((address_space(1))) void*)(gb + (size_t)64 * K + k0),
                                     (__attribute__((address_space(3))) void*)(lB + 2048), 16, 0, 0);
  };

  const int nk = KC >> 5;
  stage(0, 0);
  __syncthreads();                  // drain prologue loads
  int buf = 0;
  for (int t = 0; t < nk; ++t) {
    if (t + 1 < nk) stage(buf ^ 1, (t + 1) * 32);  // issue next-tile loads (in flight over MFMA)
    short8 af[4], bfr[4];
#pragma unroll
    for (int m = 0; m < 4; ++m)
      af[m] = *(const short8*)(As[buf] + (wr + m * 16 + fr) * 32 + ((fs ^ (fr & 3)) * 8));
#pragma unroll
    for (int n = 0; n < 4; ++n)
      bfr[n] = *(const short8*)(Bs[buf] + (wc + n * 16 + fr) * 32 + ((fs ^ (fr & 3)) * 8));
#pragma unroll
    for (int m = 0; m < 4; ++m)
#pragma unroll
      for (int n = 0; n < 4; ++n)
        acc[m][n] = MFMA_BF16(af[m], bfr[n], acc[m][n], 0, 0, 0);
    __syncthreads();                // vmcnt(0)+barrier: next tile staged, this buf free
    buf ^= 1;
  }
#pragma unroll
  for (int m = 0; m < 4; ++m)
#pragma unroll
    for (int n = 0; n < 4; ++n)
#pragma unroll
      for (int j = 0; j < 4; ++j)
        C[(brow + wr + m * 16 + fs * 4 + j) * (size_t)N + bcol + wc + n * 16 + fr] = acc[m][n][j];
}

// ---------------- fused split-K reduce + QK-RMSNorm + RoPE + head-major scatter ----------------
// qkv partials: qkvA/qkvB [N][3072] fp32 (q 0:2048 | k 2048:2560 | v 2560:3072); row = A + B
// qb: [H][N][64] bf16 (Q pre-scaled by D^-0.5 * log2e) ; kb: [KV][N][64] ; vbt: [KV][64][N]
__global__ __launch_bounds__(256) void prep_kernel(const float* __restrict__ qkv,
                                                   const float* __restrict__ qw,
                                                   const float* __restrict__ kw,
                                                   const float* __restrict__ cosT,
                                                   const float* __restrict__ sinT,
                                                   short* __restrict__ qb,
                                                   short* __restrict__ kb,
                                                   short* __restrict__ vbt) {
  const int n = blockIdx.x, t = threadIdx.x;
  const int w = t >> 6, lane = t & 63;
  __shared__ float redq[4], redk[4];
  const float* rowA = qkv + (size_t)n * 3072;
  const float* rowB = rowA + 6291456;  // second z-partial
  const float* cT = cosT + n * 32;
  const float* sT = sinT + n * 32;
  // --- Q: 2048 elems, 8/thread, norm over full 2048 ---
  const float4* r4a = (const float4*)rowA;
  const float4* r4b = (const float4*)rowB;
  float4 a0 = r4a[t * 2], a1 = r4b[t * 2];
  float4 b0 = r4a[t * 2 + 1], b1 = r4b[t * 2 + 1];
  float4 a = make_float4(a0.x + a1.x, a0.y + a1.y, a0.z + a1.z, a0.w + a1.w);
  float4 b = make_float4(b0.x + b1.x, b0.y + b1.y, b0.z + b1.z, b0.w + b1.w);
  float ss = a.x*a.x + a.y*a.y + a.z*a.z + a.w*a.w + b.x*b.x + b.y*b.y + b.z*b.z + b.w*b.w;
#pragma unroll
  for (int off = 32; off > 0; off >>= 1) ss += __shfl_xor(ss, off);
  if (lane == 0) redq[w] = ss;
  __syncthreads();
  // fold D^-0.5 and log2(e) (scores in log2-domain for exp2-based softmax)
  float rsq = rsqrtf((redq[0] + redq[1] + redq[2] + redq[3]) * (1.0f / 2048.f) + 1e-6f)
              * 0.125f * 1.44269504088896f;
  const int base = t * 8;
  float y[8] = {a.x, a.y, a.z, a.w, b.x, b.y, b.z, b.w};
#pragma unroll
  for (int e = 0; e < 8; ++e) y[e] *= rsq * qw[base + e];
  short8 ov;
  const int dbase = base & 63;
#pragma unroll
  for (int p = 0; p < 4; ++p) {
    float c = cT[(dbase >> 1) + p], s = sT[(dbase >> 1) + p];
    float x1 = y[2 * p], x2 = y[2 * p + 1];
    ov[2 * p]     = (short)f2bf(x1 * c - x2 * s);
    ov[2 * p + 1] = (short)f2bf(x1 * s + x2 * c);
  }
  const int h = base >> 6;
  *(short8*)(qb + ((size_t)h * 2048 + n) * 64 + dbase) = ov;
  // --- K: 512 elems, 2/thread, norm over full 512 ---
  const int ki = t * 2;
  float2 k0 = *(const float2*)(rowA + 2048 + ki);
  float2 k1 = *(const float2*)(rowB + 2048 + ki);
  float2 kv2 = make_float2(k0.x + k1.x, k0.y + k1.y);
  float ssk = kv2.x * kv2.x + kv2.y * kv2.y;
#pragma unroll
  for (int off = 32; off > 0; off >>= 1) ssk += __shfl_xor(ssk, off);
  if (lane == 0) redk[w] = ssk;
  __syncthreads();
  float rsk = rsqrtf((redk[0] + redk[1] + redk[2] + redk[3]) * (1.0f / 512.f) + 1e-6f);
  float z0 = kv2.x * rsk * kw[ki], z1 = kv2.y * rsk * kw[ki + 1];
  const int kd = ki & 63, kvh = ki >> 6;
  {
    float c = cT[kd >> 1], s = sT[kd >> 1];
    ushort2 o2 = make_ushort2(f2bf(z0 * c - z1 * s), f2bf(z0 * s + z1 * c));
    *(ushort2*)(kb + ((size_t)kvh * 2048 + n) * 64 + kd) = o2;
  }
  // --- V: bf16 + transpose store [KV][64][N] ---
  float2 v0 = *(const float2*)(rowA + 2560 + ki);
  float2 v1 = *(const float2*)(rowB + 2560 + ki);
  vbt[((size_t)kvh * 64 + kd) * 2048 + n]       = (short)f2bf(v0.x + v1.x);
  vbt[((size_t)kvh * 64 + kd + 1) * 2048 + n]   = (short)f2bf(v0.y + v1.y);
}

// ---------------- causal GQA flash attention v4 ----------------
// 1D grid of 1024 blocks, longest-first (qblk = 31 - bid>>5) for LPT balance.
// Block = (head, 64 q-rows); 4 waves * 16 rows. KVBLK=64. LDS = 40 KB -> 4 blocks/CU.
__global__ __launch_bounds__(256, 4) void attn_kernel(const short* __restrict__ qb,
                                                      const short* __restrict__ kb,
                                                      const short* __restrict__ vbt,
                                                      short* __restrict__ ab) {
  const int bid = blockIdx.x;
  const int h = bid & 31;
  const int qblk = 31 - (bid >> 5);       // longest blocks dispatch first
  const int kvh = h >> 2;                 // G=4
  const int tid = threadIdx.x;
  const int w = tid >> 6, lane = tid & 63;
  const int fr = lane & 15, fs = lane >> 4;
  const int q0w = qblk * 64 + w * 16;     // this wave's first q row
  __shared__ __align__(16) short Ks[2][64][64];  // [buf][kv][d], chunk c holds global chunk c^(kv&7)
  __shared__ __align__(16) short Vs[2][64][64];  // [buf][d][kv], chunk c holds global chunk c^(d&7)
  __shared__ __align__(16) short Ps[4][16][64];  // per-wave P, chunk-XOR-swizzled (no pad)
  const short* Kb = kb + (size_t)kvh * 2048 * 64;
  const short* Vb = vbt + (size_t)kvh * 64 * 2048;
  short8 qf[2];
  {
    const short* qrow = qb + ((size_t)h * 2048 + q0w + fr) * 64;
    qf[0] = *(const short8*)(qrow + fs * 8);
    qf[1] = *(const short8*)(qrow + 32 + fs * 8);
  }
  short8 ones8;
#pragma unroll
  for (int e = 0; e < 8; ++e) ones8[e] = (short)0x3F80;  // bf16 1.0
  f32x4 accO[4] = {};
  f32x4 lacc = {};                         // row-sum accumulator (via ones-MFMA)
  float mrow[4] = {-1e30f, -1e30f, -1e30f, -1e30f};

  const int rS = lane >> 3;               // staging row within 8-row strip
  const int cS = (lane & 7) ^ rS;         // pre-swizzled source chunk
  auto stage = [&](int sb, int kv0s) {
#pragma unroll
    for (int i = 0; i < 2; ++i) {
      int r = i * 32 + w * 8 + rS;        // r & 7 == rS
      __builtin_amdgcn_global_load_lds(
          (__attribute__((address_space(1))) void*)(Kb + (size_t)(kv0s + r) * 64 + cS * 8),
          (__attribute__((address_space(3))) void*)(&Ks[sb][0][0] + i * 2048 + w * 512), 16, 0, 0);
      __builtin_amdgcn_global_load_lds(
          (__attribute__((address_space(1))) void*)(Vb + (size_t)r * 2048 + kv0s + cS * 8),
          (__attribute__((address_space(3))) void*)(&Vs[sb][0][0] + i * 2048 + w * 512), 16, 0, 0);
    }
  };

  const int ntiles = qblk + 1;
  int buf = 0;
  stage(0, 0);
  __syncthreads();
  for (int t = 0; t < ntiles; ++t) {
    const int kv0 = t * 64;
    if (t + 1 < ntiles) stage(buf ^ 1, (t + 1) * 64);
    const short* KsB = &Ks[buf][0][0];
    const short* VsB = &Vs[buf][0][0];
    const int sw = (fr & 7);
    // ---- QK^T (scores in log2-domain; Q pre-scaled by D^-0.5*log2e) ----
    f32x4 sc[4];
#pragma unroll
    for (int ct = 0; ct < 4; ++ct) {
      const int rk = ct * 16 + fr;
      short8 kf0 = *(const short8*)(KsB + rk * 64 + ((fs ^ sw) * 8));
      short8 kf1 = *(const short8*)(KsB + rk * 64 + (((4 + fs) ^ sw) * 8));
      f32x4 a = {};
      a = MFMA_BF16(qf[0], kf0, a, 0, 0, 0);
      a = MFMA_BF16(qf[1], kf1, a, 0, 0, 0);
      sc[ct] = a;
    }
    // ---- causal mask (exactly the last tile per wave) ----
    if (t == qblk) {
#pragma unroll
      for (int ct = 0; ct < 4; ++ct) {
        const int col = kv0 + ct * 16 + fr;
#pragma unroll
        for (int j = 0; j < 4; ++j)
          if (col > q0w + fs * 4 + j) sc[ct][j] = -1e30f;
      }
    }
    // ---- online softmax: row max + defer-max (T13, THR=8 in log2-domain) ----
    float pmax[4];
    int defer_ok = 1;
#pragma unroll
    for (int j = 0; j < 4; ++j) {
      float v = fmaxf(fmaxf(sc[0][j], sc[1][j]), fmaxf(sc[2][j], sc[3][j]));
#pragma unroll
      for (int off = 1; off < 16; off <<= 1) v = fmaxf(v, __shfl_xor(v, off));
      pmax[j] = v;
      defer_ok &= (v - mrow[j] <= 8.0f);
    }
    if (!__all(defer_ok)) {  // rescale path (rare after warm-up)
      float resc[4];
#pragma unroll
      for (int j = 0; j < 4; ++j) {
        float mn = fmaxf(mrow[j], pmax[j]);
        resc[j] = exp2f(mrow[j] - mn);
        mrow[j] = mn;
        lacc[j] *= resc[j];
      }
#pragma unroll
      for (int dt = 0; dt < 4; ++dt)
#pragma unroll
        for (int j = 0; j < 4; ++j) accO[dt][j] *= resc[j];
    }
    // ---- P = exp2(sc - m), store bf16 to LDS (chunk-XOR-swizzled cols) ----
#pragma unroll
    for (int ct = 0; ct < 4; ++ct)
#pragma unroll
      for (int j = 0; j < 4; ++j) {
        const int r = fs * 4 + j;
        Ps[w][r][(ct * 16 + fr) ^ ((r & 7) << 3)] = (short)f2bf(exp2f(sc[ct][j] - mrow[j]));
      }
    // ---- P·V + row-sum via ones-MFMA ----
    short8 pa[2];
#pragma unroll
    for (int s = 0; s < 2; ++s)
      pa[s] = *(const short8*)(&Ps[w][fr][((s * 4 + fs) ^ (fr & 7)) * 8]);
    lacc = MFMA_BF16(pa[0], ones8, lacc, 0, 0, 0);
    lacc = MFMA_BF16(pa[1], ones8, lacc, 0, 0, 0);
#pragma unroll
    for (int dt = 0; dt < 4; ++dt) {
      const int rv = dt * 16 + fr;
      short8 vf0 = *(const short8*)(VsB + rv * 64 + ((fs ^ sw) * 8));
      short8 vf1 = *(const short8*)(VsB + rv * 64 + (((4 + fs) ^ sw) * 8));
      accO[dt] = MFMA_BF16(pa[0], vf0, accO[dt], 0, 0, 0);
      accO[dt] = MFMA_BF16(pa[1], vf1, accO[dt], 0, 0, 0);
    }
    __syncthreads();
    buf ^= 1;
  }
  // ---- epilogue: normalize + store [N][H*D] bf16 ----
  float invl[4];
#pragma unroll
  for (int j = 0; j < 4; ++j) invl[j] = 1.0f / lacc[j];
#pragma unroll
  for (int dt = 0; dt < 4; ++dt)
#pragma unroll
    for (int j = 0; j < 4; ++j)
      ab[(size_t)(q0w + fs * 4 + j) * 2048 + h * 64 + dt * 16 + fr] =
          (short)f2bf(accO[dt][j] * invl[j]);
}

extern "C" void kernel_launch(void* const* d_in, const int* in_sizes, int n_in,
                              void* d_out, int out_size, void* d_ws, size_t ws_size,
                              hipStream_t stream) {
  const float* x  = (const float*)d_in[0];
  const float* wq = (const float*)d_in[1];
  const float* wk = (const float*)d_in[2];
  const float* wv = (const float*)d_in[3];
  const float* wo = (const float*)d_in[4];
  const float* qw = (const float*)d_in[5];
  const float* kw = (const float*)d_in[6];
  float* out = (float*)d_out;
  char* ws = (char*)d_ws;
  short* xb    = (short*)(ws + 0);          // 8 MB  : x bf16, then attn-out bf16
  short* wb    = (short*)(ws + 8388608);    // 12 MB : [wq;wk;wv] bf16 [3072][2048]
  short* wob   = (short*)(ws + 20971520);   // 8 MB  : wo bf16
  float* qkvfA = (float*)(ws + 29360128);   // 24 MB : qkv z0 partial [2048][3072] f32
  float* qkvfB = (float*)(ws + 54525952);   // 24 MB : qkv z1 partial (contiguous after A)
  short* qb    = (short*)(ws + 79691776);   // 8 MB  : q roped+scaled [32][2048][64]
  short* kb    = (short*)(ws + 88080384);   // 2 MB  : k roped [8][2048][64]
  short* vbt   = (short*)(ws + 90177536);   // 2 MB  : v^T [8][64][2048]
  float* cosT  = (float*)(ws + 92274688);   // 256 KB
  float* sinT  = (float*)(ws + 92536832);   // 256 KB  (total ~88.5 MB)
  short* ab = xb;
  // GEMM2 partials reuse the dead qkvf region after prep (2 x 16 MB <= 48 MB)
  float* po0 = qkvfA;
  float* po1 = qkvfA + 4194304;
  (void)qkvfB; (void)ws_size;

  f2b5_kernel<<<14336, 256, 0, stream>>>(x, wq, wk, wv, wo,
                                         (unsigned short*)xb, (unsigned short*)wb,
                                         (unsigned short*)wob);
  trig_kernel<<<256, 256, 0, stream>>>(cosT, sinT);
  gemm_bt<<<dim3(24, 16, 2), 256, 0, stream>>>(xb, wb, qkvfA, 2048, 3072, 2048, 1024);
  prep_kernel<<<2048, 256, 0, stream>>>(qkvfA, qw, kw, cosT, sinT, qb, kb, vbt);
  attn_kernel<<<1024, 256, 0, stream>>>(qb, kb, vbt, ab);
  gemm_bt<<<dim3(16, 16, 2), 256, 0, stream>>>(ab, wob, po0, 2048, 2048, 2048, 1024);
  add2_kernel<<<2048, 256, 0, stream>>>(po0, po1, out);
}

// Round 7
// 166.755 us; speedup vs baseline: 1.4052x; 1.0005x over previous
//
#include <hip/hip_runtime.h>

typedef __attribute__((ext_vector_type(8))) short short8;
typedef __attribute__((ext_vector_type(4))) float f32x4;

#define MFMA_BF16 __builtin_amdgcn_mfma_f32_16x16x32_bf16

__device__ __forceinline__ unsigned short f2bf(float f) {
  unsigned u = __builtin_bit_cast(unsigned, f);
  u += 0x7fffu + ((u >> 16) & 1u);
  return (unsigned short)(u >> 16);
}

// ---------------- fused fp32 -> bf16 convert for all 5 inputs ----------------
__global__ __launch_bounds__(256) void f2b5_kernel(const float* __restrict__ x,
                                                   const float* __restrict__ wq,
                                                   const float* __restrict__ wk,
                                                   const float* __restrict__ wv,
                                                   const float* __restrict__ wo,
                                                   unsigned short* __restrict__ xb,
                                                   unsigned short* __restrict__ wb,
                                                   unsigned short* __restrict__ wob) {
  const int b = blockIdx.x;
  const float* src;
  unsigned short* dst;
  int base;
  if (b < 4096)      { src = x;  dst = xb;                base = b; }
  else if (b < 8192) { src = wq; dst = wb;                base = b - 4096; }
  else if (b < 9216) { src = wk; dst = wb + 2048 * 2048;  base = b - 8192; }
  else if (b < 10240){ src = wv; dst = wb + 2560 * 2048;  base = b - 9216; }
  else               { src = wo; dst = wob;               base = b - 10240; }
  const int i = base * 256 + threadIdx.x;
  const float4 v = ((const float4*)src)[i];
  ushort4 o = make_ushort4(f2bf(v.x), f2bf(v.y), f2bf(v.z), f2bf(v.w));
  ((ushort4*)dst)[i] = o;
}

// ---------------- RoPE trig table: [N][32] cos/sin (f64 once, tiny) ----------------
__global__ __launch_bounds__(256) void trig_kernel(float* __restrict__ cosT, float* __restrict__ sinT) {
  int i = blockIdx.x * 256 + threadIdx.x;  // [0, 2048*32)
  int n = i >> 5, f = i & 31;
  double ang = (double)n * pow(10000.0, -(double)f / 32.0);
  cosT[i] = (float)cos(ang);
  sinT[i] = (float)sin(ang);
}

// ---------------- split-K partial reduce: out = a + b (float4 x2 per thread) ----------------
__global__ __launch_bounds__(256) void add2_kernel(const float* __restrict__ a,
                                                   const float* __restrict__ b,
                                                   float* __restrict__ o) {
  int i = blockIdx.x * 256 + threadIdx.x;
#pragma unroll
  for (int s = 0; s < 2; ++s) {
    const float4 u = ((const float4*)a)[i], v = ((const float4*)b)[i];
    ((float4*)o)[i] = make_float4(u.x + v.x, u.y + v.y, u.z + v.z, u.w + v.w);
    i += 524288;
  }
}

// ---------------- bf16 NT GEMM, 2-phase double-buffered, split-K to partials ----------------
// C_z[M][N] = A[M][Kchunk_z] * B[N][Kchunk_z]^T ; z-slice writes C + z*M*N (plain stores).
// LDS chunk-XOR swizzle: LDS chunk c of row r holds global chunk c^(r&3)  (pre-swizzled src).
__global__ __launch_bounds__(256) void gemm_bt(const short* __restrict__ A,
                                               const short* __restrict__ B,
                                               float* __restrict__ C,
                                               int M, int N, int K, int KC) {
  __shared__ __align__(16) short As[2][128 * 32];
  __shared__ __align__(16) short Bs[2][128 * 32];
  const int tid = threadIdx.x;
  const int w = tid >> 6, lane = tid & 63;
  const int fr = lane & 15, fs = lane >> 4;
  const size_t brow = (size_t)blockIdx.y * 128, bcol = (size_t)blockIdx.x * 128;
  const int wr = (w >> 1) * 64, wc = (w & 1) * 64;
  const int lr = tid >> 2;          // staging row 0..63 (+64 for 2nd issue)
  const int lcS = ((tid & 3) ^ (lr & 3)) * 8;  // pre-swizzled source chunk (8 bf16 = 16B)
  const int ks = blockIdx.z * KC;
  C += (size_t)blockIdx.z * ((size_t)M * N);   // partial buffer for this z-slice
  const short* ga = A + (brow + lr) * (size_t)K + lcS + ks;
  const short* gb = B + (bcol + lr) * (size_t)K + lcS + ks;
  f32x4 acc[4][4] = {};

  auto stage = [&](int sb, int k0) {
    short* lA = As[sb] + w * 512;   // wave-uniform LDS dest (HW: base + lane*16B)
    short* lB = Bs[sb] + w * 512;
    __builtin_amdgcn_global_load_lds((__attribute__((address_space(1))) void*)(ga + k0),
                                     (__attribute__((address_space(3))) void*)(lA), 16, 0, 0);
    __builtin_amdgcn_global_load_lds((__attribute__((address_space(1))) void*)(ga + (size_t)64 * K + k0),
                                     (__attribute__((address_space(3))) void*)(lA + 2048), 16, 0, 0);
    __builtin_amdgcn_global_load_lds((__attribute__((address_space(1))) void*)(gb + k0),
                                     (__attribute__((address_space(3))) void*)(lB), 16, 0, 0);
    __builtin_amdgcn_global_load_lds((__attribute__((address_space(1))) void*)(gb + (size_t)64 * K + k0),
                                     (__attribute__((address_space(3))) void*)(lB + 2048), 16, 0, 0);
  };

  const int nk = KC >> 5;
  stage(0, 0);
  __syncthreads();                  // drain prologue loads
  int buf = 0;
  for (int t = 0; t < nk; ++t) {
    if (t + 1 < nk) stage(buf ^ 1, (t + 1) * 32);  // issue next-tile loads (in flight over MFMA)
    short8 af[4], bfr[4];
#pragma unroll
    for (int m = 0; m < 4; ++m)
      af[m] = *(const short8*)(As[buf] + (wr + m * 16 + fr) * 32 + ((fs ^ (fr & 3)) * 8));
#pragma unroll
    for (int n = 0; n < 4; ++n)
      bfr[n] = *(const short8*)(Bs[buf] + (wc + n * 16 + fr) * 32 + ((fs ^ (fr & 3)) * 8));
#pragma unroll
    for (int m = 0; m < 4; ++m)
#pragma unroll
      for (int n = 0; n < 4; ++n)
        acc[m][n] = MFMA_BF16(af[m], bfr[n], acc[m][n], 0, 0, 0);
    __syncthreads();                // vmcnt(0)+barrier: next tile staged, this buf free
    buf ^= 1;
  }
#pragma unroll
  for (int m = 0; m < 4; ++m)
#pragma unroll
    for (int n = 0; n < 4; ++n)
#pragma unroll
      for (int j = 0; j < 4; ++j)
        C[(brow + wr + m * 16 + fs * 4 + j) * (size_t)N + bcol + wc + n * 16 + fr] = acc[m][n][j];
}

// ---------------- fused split-K reduce + QK-RMSNorm + RoPE + head-major scatter ----------------
// qkv partials: qkvA/qkvB [N][3072] fp32 (q 0:2048 | k 2048:2560 | v 2560:3072); row = A + B
// qb: [H][N][64] bf16 (Q pre-scaled by D^-0.5 * log2e) ; kb: [KV][N][64] ; vbt: [KV][64][N]
__global__ __launch_bounds__(256) void prep_kernel(const float* __restrict__ qkv,
                                                   const float* __restrict__ qw,
                                                   const float* __restrict__ kw,
                                                   const float* __restrict__ cosT,
                                                   const float* __restrict__ sinT,
                                                   short* __restrict__ qb,
                                                   short* __restrict__ kb,
                                                   short* __restrict__ vbt) {
  const int n = blockIdx.x, t = threadIdx.x;
  const int w = t >> 6, lane = t & 63;
  __shared__ float redq[4], redk[4];
  const float* rowA = qkv + (size_t)n * 3072;
  const float* rowB = rowA + 6291456;  // second z-partial
  const float* cT = cosT + n * 32;
  const float* sT = sinT + n * 32;
  // --- Q: 2048 elems, 8/thread, norm over full 2048 ---
  const float4* r4a = (const float4*)rowA;
  const float4* r4b = (const float4*)rowB;
  float4 a0 = r4a[t * 2], a1 = r4b[t * 2];
  float4 b0 = r4a[t * 2 + 1], b1 = r4b[t * 2 + 1];
  float4 a = make_float4(a0.x + a1.x, a0.y + a1.y, a0.z + a1.z, a0.w + a1.w);
  float4 b = make_float4(b0.x + b1.x, b0.y + b1.y, b0.z + b1.z, b0.w + b1.w);
  float ss = a.x*a.x + a.y*a.y + a.z*a.z + a.w*a.w + b.x*b.x + b.y*b.y + b.z*b.z + b.w*b.w;
#pragma unroll
  for (int off = 32; off > 0; off >>= 1) ss += __shfl_xor(ss, off);
  if (lane == 0) redq[w] = ss;
  __syncthreads();
  // fold D^-0.5 and log2(e) (scores in log2-domain for exp2-based softmax)
  float rsq = rsqrtf((redq[0] + redq[1] + redq[2] + redq[3]) * (1.0f / 2048.f) + 1e-6f)
              * 0.125f * 1.44269504088896f;
  const int base = t * 8;
  float y[8] = {a.x, a.y, a.z, a.w, b.x, b.y, b.z, b.w};
#pragma unroll
  for (int e = 0; e < 8; ++e) y[e] *= rsq * qw[base + e];
  short8 ov;
  const int dbase = base & 63;
#pragma unroll
  for (int p = 0; p < 4; ++p) {
    float c = cT[(dbase >> 1) + p], s = sT[(dbase >> 1) + p];
    float x1 = y[2 * p], x2 = y[2 * p + 1];
    ov[2 * p]     = (short)f2bf(x1 * c - x2 * s);
    ov[2 * p + 1] = (short)f2bf(x1 * s + x2 * c);
  }
  const int h = base >> 6;
  *(short8*)(qb + ((size_t)h * 2048 + n) * 64 + dbase) = ov;
  // --- K: 512 elems, 2/thread, norm over full 512 ---
  const int ki = t * 2;
  float2 k0 = *(const float2*)(rowA + 2048 + ki);
  float2 k1 = *(const float2*)(rowB + 2048 + ki);
  float2 kv2 = make_float2(k0.x + k1.x, k0.y + k1.y);
  float ssk = kv2.x * kv2.x + kv2.y * kv2.y;
#pragma unroll
  for (int off = 32; off > 0; off >>= 1) ssk += __shfl_xor(ssk, off);
  if (lane == 0) redk[w] = ssk;
  __syncthreads();
  float rsk = rsqrtf((redk[0] + redk[1] + redk[2] + redk[3]) * (1.0f / 512.f) + 1e-6f);
  float z0 = kv2.x * rsk * kw[ki], z1 = kv2.y * rsk * kw[ki + 1];
  const int kd = ki & 63, kvh = ki >> 6;
  {
    float c = cT[kd >> 1], s = sT[kd >> 1];
    ushort2 o2 = make_ushort2(f2bf(z0 * c - z1 * s), f2bf(z0 * s + z1 * c));
    *(ushort2*)(kb + ((size_t)kvh * 2048 + n) * 64 + kd) = o2;
  }
  // --- V: bf16 + transpose store [KV][64][N] ---
  float2 v0 = *(const float2*)(rowA + 2560 + ki);
  float2 v1 = *(const float2*)(rowB + 2560 + ki);
  vbt[((size_t)kvh * 64 + kd) * 2048 + n]       = (short)f2bf(v0.x + v1.x);
  vbt[((size_t)kvh * 64 + kd + 1) * 2048 + n]   = (short)f2bf(v0.y + v1.y);
}

// ---------------- causal GQA flash attention v5: triangular pairing ----------------
// Block = (head, pair p): q-blocks lo=p and hi=31-p; every block does exactly 33
// tile-computations (perfect balance). 512 blocks, 4 waves; each wave owns 16 rows
// of BOTH q-blocks (hi always active, lo active while t<=p; wave-uniform).
// LDS 48 KB. K/V double-buffered via global_load_lds w=16 with pre-swizzled src.
__global__ __launch_bounds__(256, 2) void attn_kernel(const short* __restrict__ qb,
                                                      const short* __restrict__ kb,
                                                      const short* __restrict__ vbt,
                                                      short* __restrict__ ab) {
  const int bid = blockIdx.x;
  const int h = bid & 31;
  const int p = bid >> 5;                 // 0..15
  const int lo = p, hi = 31 - p;
  const int kvh = h >> 2;                 // G=4
  const int tid = threadIdx.x;
  const int w = tid >> 6, lane = tid & 63;
  const int fr = lane & 15, fs = lane >> 4;
  const int q0lo = lo * 64 + w * 16;
  const int q0hi = hi * 64 + w * 16;
  __shared__ __align__(16) short Ks[2][64][64];   // [buf][kv][d], chunk c holds global chunk c^(kv&7)
  __shared__ __align__(16) short Vs[2][64][64];   // [buf][d][kv], chunk c holds global chunk c^(d&7)
  __shared__ __align__(16) short Ps[4][2][16][64];// per-wave per-group P, chunk-XOR-swizzled
  const short* Kb = kb + (size_t)kvh * 2048 * 64;
  const short* Vb = vbt + (size_t)kvh * 64 * 2048;
  short8 qfH[2], qfL[2];
  {
    const short* qrowH = qb + ((size_t)h * 2048 + q0hi + fr) * 64;
    const short* qrowL = qb + ((size_t)h * 2048 + q0lo + fr) * 64;
    qfH[0] = *(const short8*)(qrowH + fs * 8);
    qfH[1] = *(const short8*)(qrowH + 32 + fs * 8);
    qfL[0] = *(const short8*)(qrowL + fs * 8);
    qfL[1] = *(const short8*)(qrowL + 32 + fs * 8);
  }
  short8 ones8;
#pragma unroll
  for (int e = 0; e < 8; ++e) ones8[e] = (short)0x3F80;  // bf16 1.0
  f32x4 accH[4] = {}, accL[4] = {};
  f32x4 laccH = {}, laccL = {};
  float mrowH[4] = {-1e30f, -1e30f, -1e30f, -1e30f};
  float mrowL[4] = {-1e30f, -1e30f, -1e30f, -1e30f};

  const int rS = lane >> 3;               // staging row within 8-row strip
  const int cS = (lane & 7) ^ rS;         // pre-swizzled source chunk
  auto stage = [&](int sb, int kv0s) {
#pragma unroll
    for (int i = 0; i < 2; ++i) {
      int r = i * 32 + w * 8 + rS;        // r & 7 == rS
      __builtin_amdgcn_global_load_lds(
          (__attribute__((address_space(1))) void*)(Kb + (size_t)(kv0s + r) * 64 + cS * 8),
          (__attribute__((address_space(3))) void*)(&Ks[sb][0][0] + i * 2048 + w * 512), 16, 0, 0);
      __builtin_amdgcn_global_load_lds(
          (__attribute__((address_space(1))) void*)(Vb + (size_t)r * 2048 + kv0s + cS * 8),
          (__attribute__((address_space(3))) void*)(&Vs[sb][0][0] + i * 2048 + w * 512), 16, 0, 0);
    }
  };

  const int ntiles = 32 - p;              // hi's tile count (lo's range is a prefix)
  int buf = 0;
  stage(0, 0);
  __syncthreads();
  for (int t = 0; t < ntiles; ++t) {
    const int kv0 = t * 64;
    if (t + 1 < ntiles) stage(buf ^ 1, (t + 1) * 64);
    const short* KsB = &Ks[buf][0][0];
    const short* VsB = &Vs[buf][0][0];
    const int sw = (fr & 7);

    auto proc = [&](const short8 (&qf)[2], f32x4 (&accO)[4], f32x4& lacc, float (&mrow)[4],
                    short (*PsG)[64], int q0, bool domask) {
      // ---- QK^T (log2-domain; Q pre-scaled by D^-0.5*log2e) ----
      f32x4 sc[4];
#pragma unroll
      for (int ct = 0; ct < 4; ++ct) {
        const int rk = ct * 16 + fr;
        short8 kf0 = *(const short8*)(KsB + rk * 64 + ((fs ^ sw) * 8));
        short8 kf1 = *(const short8*)(KsB + rk * 64 + (((4 + fs) ^ sw) * 8));
        f32x4 a = {};
        a = MFMA_BF16(qf[0], kf0, a, 0, 0, 0);
        a = MFMA_BF16(qf[1], kf1, a, 0, 0, 0);
        sc[ct] = a;
      }
      // ---- causal mask (one tile per group) ----
      if (domask) {
#pragma unroll
        for (int ct = 0; ct < 4; ++ct) {
          const int col = kv0 + ct * 16 + fr;
#pragma unroll
          for (int j = 0; j < 4; ++j)
            if (col > q0 + fs * 4 + j) sc[ct][j] = -1e30f;
        }
      }
      // ---- online softmax: row max + defer-max (T13, THR=8 in log2-domain) ----
      float pmax[4];
      int defer_ok = 1;
#pragma unroll
      for (int j = 0; j < 4; ++j) {
        float v = fmaxf(fmaxf(sc[0][j], sc[1][j]), fmaxf(sc[2][j], sc[3][j]));
#pragma unroll
        for (int off = 1; off < 16; off <<= 1) v = fmaxf(v, __shfl_xor(v, off));
        pmax[j] = v;
        defer_ok &= (v - mrow[j] <= 8.0f);
      }
      if (!__all(defer_ok)) {  // rescale path (rare after warm-up)
        float resc[4];
#pragma unroll
        for (int j = 0; j < 4; ++j) {
          float mn = fmaxf(mrow[j], pmax[j]);
          resc[j] = exp2f(mrow[j] - mn);
          mrow[j] = mn;
          lacc[j] *= resc[j];
        }
#pragma unroll
        for (int dt = 0; dt < 4; ++dt)
#pragma unroll
          for (int j = 0; j < 4; ++j) accO[dt][j] *= resc[j];
      }
      // ---- P = exp2(sc - m), bf16 to LDS (chunk-XOR-swizzled cols) ----
#pragma unroll
      for (int ct = 0; ct < 4; ++ct)
#pragma unroll
        for (int j = 0; j < 4; ++j) {
          const int r = fs * 4 + j;
          PsG[r][(ct * 16 + fr) ^ ((r & 7) << 3)] = (short)f2bf(exp2f(sc[ct][j] - mrow[j]));
        }
      // ---- P·V + row-sum via ones-MFMA ----
      short8 pa[2];
#pragma unroll
      for (int s = 0; s < 2; ++s)
        pa[s] = *(const short8*)(&PsG[fr][((s * 4 + fs) ^ (fr & 7)) * 8]);
      __builtin_amdgcn_s_setprio(1);
      lacc = MFMA_BF16(pa[0], ones8, lacc, 0, 0, 0);
      lacc = MFMA_BF16(pa[1], ones8, lacc, 0, 0, 0);
#pragma unroll
      for (int dt = 0; dt < 4; ++dt) {
        const int rv = dt * 16 + fr;
        short8 vf0 = *(const short8*)(VsB + rv * 64 + ((fs ^ sw) * 8));
        short8 vf1 = *(const short8*)(VsB + rv * 64 + (((4 + fs) ^ sw) * 8));
        accO[dt] = MFMA_BF16(pa[0], vf0, accO[dt], 0, 0, 0);
        accO[dt] = MFMA_BF16(pa[1], vf1, accO[dt], 0, 0, 0);
      }
      __builtin_amdgcn_s_setprio(0);
    };

    proc(qfH, accH, laccH, mrowH, Ps[w][0], q0hi, t == ntiles - 1);
    if (t <= lo) proc(qfL, accL, laccL, mrowL, Ps[w][1], q0lo, t == lo);
    __syncthreads();
    buf ^= 1;
  }
  // ---- epilogue: normalize + store [N][H*D] bf16 for both groups ----
#pragma unroll
  for (int g = 0; g < 2; ++g) {
    const f32x4* accO = g ? accL : accH;
    const f32x4& lacc = g ? laccL : laccH;
    const int q0 = g ? q0lo : q0hi;
    float invl[4];
#pragma unroll
    for (int j = 0; j < 4; ++j) invl[j] = 1.0f / lacc[j];
#pragma unroll
    for (int dt = 0; dt < 4; ++dt)
#pragma unroll
      for (int j = 0; j < 4; ++j)
        ab[(size_t)(q0 + fs * 4 + j) * 2048 + h * 64 + dt * 16 + fr] =
            (short)f2bf(accO[dt][j] * invl[j]);
  }
}

extern "C" void kernel_launch(void* const* d_in, const int* in_sizes, int n_in,
                              void* d_out, int out_size, void* d_ws, size_t ws_size,
                              hipStream_t stream) {
  const float* x  = (const float*)d_in[0];
  const float* wq = (const float*)d_in[1];
  const float* wk = (const float*)d_in[2];
  const float* wv = (const float*)d_in[3];
  const float* wo = (const float*)d_in[4];
  const float* qw = (const float*)d_in[5];
  const float* kw = (const float*)d_in[6];
  float* out = (float*)d_out;
  char* ws = (char*)d_ws;
  short* xb    = (short*)(ws + 0);          // 8 MB  : x bf16, then attn-out bf16
  short* wb    = (short*)(ws + 8388608);    // 12 MB : [wq;wk;wv] bf16 [3072][2048]
  short* wob   = (short*)(ws + 20971520);   // 8 MB  : wo bf16
  float* qkvfA = (float*)(ws + 29360128);   // 24 MB : qkv z0 partial [2048][3072] f32
  float* qkvfB = (float*)(ws + 54525952);   // 24 MB : qkv z1 partial (contiguous after A)
  short* qb    = (short*)(ws + 79691776);   // 8 MB  : q roped+scaled [32][2048][64]
  short* kb    = (short*)(ws + 88080384);   // 2 MB  : k roped [8][2048][64]
  short* vbt   = (short*)(ws + 90177536);   // 2 MB  : v^T [8][64][2048]
  float* cosT  = (float*)(ws + 92274688);   // 256 KB
  float* sinT  = (float*)(ws + 92536832);   // 256 KB  (total ~88.5 MB)
  short* ab = xb;
  // GEMM2 partials reuse the dead qkvf region after prep (2 x 16 MB <= 48 MB)
  float* po0 = qkvfA;
  float* po1 = qkvfA + 4194304;
  (void)qkvfB; (void)ws_size;

  f2b5_kernel<<<14336, 256, 0, stream>>>(x, wq, wk, wv, wo,
                                         (unsigned short*)xb, (unsigned short*)wb,
                                         (unsigned short*)wob);
  trig_kernel<<<256, 256, 0, stream>>>(cosT, sinT);
  gemm_bt<<<dim3(24, 16, 2), 256, 0, stream>>>(xb, wb, qkvfA, 2048, 3072, 2048, 1024);
  prep_kernel<<<2048, 256, 0, stream>>>(qkvfA, qw, kw, cosT, sinT, qb, kb, vbt);
  attn_kernel<<<512, 256, 0, stream>>>(qb, kb, vbt, ab);
  gemm_bt<<<dim3(16, 16, 2), 256, 0, stream>>>(ab, wob, po0, 2048, 2048, 2048, 1024);
  add2_kernel<<<2048, 256, 0, stream>>>(po0, po1, out);
}